// Round 8
// baseline (554.929 us; speedup 1.0000x reference)
//
#include <hip/hip_runtime.h>
#include <vector>
#include <algorithm>
#include <utility>

typedef unsigned long long u64;
typedef unsigned int u32;

#define NTRIP 110592              // 48^3 distinct (c0,c1,c2)
#define LOGB 18
#define NBUCK (1u << LOGB)        // 262144 buckets over the 23-bit key space
#define IDXBITS 21
#define IMASK ((1u << IDXBITS) - 1)
#define SCAN_T 256
#define SCAN_E 8
#define SCAN_CHUNK 2048
#define SORT_WAVES 4
#define LDS_CAP 512

// ======== host-side: rank table for the 110,592 triple-hashes ========
// full hash = fnv3p(c0,c1,c2) ^ c3 (c3 < 64 flips only low 6 bits).
// rank48[tau] = (rank_of_hash << 6) | (hash & 63); point key = rank48[tau]^c3 (23 bits)
static u32 g_rank48[NTRIP];
namespace {
struct RankInit {
    RankInit() {
        std::vector<std::pair<u64, u32>> v(NTRIP);
        for (u32 t = 0; t < NTRIP; t++) {
            u64 h = 14695981039346656037ull;
            const u64 P = 1099511628211ull;
            h *= P; h ^= (u64)(t / 2304);
            h *= P; h ^= (u64)((t % 2304) / 48);
            h *= P; h ^= (u64)(t % 48);
            h *= P;
            v[t] = {h, t};
        }
        std::sort(v.begin(), v.end());
        for (u32 p = 0; p < NTRIP; p++)
            g_rank48[v[p].second] = (p << 6) | (u32)(v[p].first & 63ull);
    }
};
static RankInit g_rank_init;
}

// invrank[rank] = (tau<<6) | (t&63)  -- inverse of rank48
__global__ void k_invrank(const u32* __restrict__ rank48, u32* __restrict__ invrank) {
    int tau = blockIdx.x * blockDim.x + threadIdx.x;
    if (tau >= NTRIP) return;
    u32 r = rank48[tau];
    invrank[r >> 6] = ((u32)tau << 6) | (r & 63u);
}

// ======== packed point keys + bucket histogram (1MB table) ========
__global__ void k_pkeys(const int* __restrict__ coords, const u32* __restrict__ rank48,
                        u32* __restrict__ hist, u64* __restrict__ pkey64, int N) {
    int i = blockIdx.x * blockDim.x + threadIdx.x;
    if (i >= N) return;
    int4 c = ((const int4*)coords)[i];
    u32 tau = (u32)c.x * 2304u + (u32)c.y * 48u + (u32)c.z;
    u32 kk = rank48[tau] ^ (u32)c.w;
    pkey64[i] = ((u64)kk << IDXBITS) | (u32)i;
    atomicAdd(&hist[kk >> 5], 1u);
}

// ======== generic 2-level u32 scan (proven R1 code) ========
template <bool EXCL>
__global__ void k_scan_chunks(u32* data, int n, u32* sums) {
    __shared__ u32 s[SCAN_T];
    int tid = threadIdx.x;
    int idx0 = blockIdx.x * SCAN_CHUNK + tid * SCAN_E;
    u32 v[SCAN_E], o[SCAN_E];
    u32 run = 0;
#pragma unroll
    for (int k = 0; k < SCAN_E; k++) {
        int idx = idx0 + k;
        u32 x = (idx < n) ? data[idx] : 0u;
        o[k] = x; run += x; v[k] = run;
    }
    s[tid] = run;
    __syncthreads();
    for (int off = 1; off < SCAN_T; off <<= 1) {
        u32 t = (tid >= off) ? s[tid - off] : 0u;
        __syncthreads();
        s[tid] += t;
        __syncthreads();
    }
    u32 tbase = s[tid] - run;
#pragma unroll
    for (int k = 0; k < SCAN_E; k++) {
        int idx = idx0 + k;
        if (idx < n) data[idx] = tbase + v[k] - (EXCL ? o[k] : 0u);
    }
    if (tid == SCAN_T - 1 && sums) sums[blockIdx.x] = s[SCAN_T - 1];
}

__global__ void k_scan_single(u32* data, int n) {  // exclusive, n <= 2048
    __shared__ u32 s[SCAN_T];
    int tid = threadIdx.x;
    int idx0 = tid * SCAN_E;
    u32 v[SCAN_E], o[SCAN_E];
    u32 run = 0;
#pragma unroll
    for (int k = 0; k < SCAN_E; k++) {
        int idx = idx0 + k;
        u32 x = (idx < n) ? data[idx] : 0u;
        o[k] = x; run += x; v[k] = run;
    }
    s[tid] = run;
    __syncthreads();
    for (int off = 1; off < SCAN_T; off <<= 1) {
        u32 t = (tid >= off) ? s[tid - off] : 0u;
        __syncthreads();
        s[tid] += t;
        __syncthreads();
    }
    u32 tbase = s[tid] - run;
#pragma unroll
    for (int k = 0; k < SCAN_E; k++) {
        int idx = idx0 + k;
        if (idx < n) data[idx] = tbase + v[k] - o[k];
    }
}

__global__ void k_scan_add(u32* data, int n, const u32* __restrict__ sums) {
    int i = blockIdx.x * blockDim.x + threadIdx.x;
    if (i >= n) return;
    data[i] += sums[i / SCAN_CHUNK];
}

// ======== scatter packed keys into buckets ========
__global__ void k_scatter64(const u64* __restrict__ pkey64, u32* __restrict__ hist,
                            u64* __restrict__ sorted, int N) {
    int i = blockIdx.x * blockDim.x + threadIdx.x;
    if (i >= N) return;
    u64 p = pkey64[i];
    u32 b = (u32)(p >> (IDXBITS + 5));   // kk >> 5
    u32 pos = atomicAdd(&hist[b], 1u);
    sorted[pos] = p;
}

// ======== wave-per-bucket sort on packed (key,idx) + distinct-key count ========
__global__ void k_bucket_sort64(const u32* __restrict__ hist, u64* __restrict__ sorted,
                                u32* __restrict__ dcount) {
    __shared__ u64 li[SORT_WAVES][LDS_CAP];
    __shared__ u64 lo[SORT_WAVES][LDS_CAP];
    int w = threadIdx.x >> 6;
    int lane = threadIdx.x & 63;
    u32 b = blockIdx.x * SORT_WAVES + (u32)w;
    if (b >= NBUCK) return;
    int end = (int)hist[b];
    int start = b ? (int)hist[b - 1] : 0;
    int s = end - start;
    if (s <= 1) {
        if (lane == 0) dcount[b] = (u32)s;
        return;
    }
    if (s <= 64) {
        u64 p = ~0ull;
        if (lane < s) p = sorted[start + lane];
        u32 mykey = (u32)(p >> IDXBITS);
        int rank = 0, same = 0;
        for (int j = 0; j < s; j++) {
            u64 pj = __shfl(p, j);
            bool less = pj < p;
            rank += less ? 1 : 0;
            same += (less && ((u32)(pj >> IDXBITS) == mykey)) ? 1 : 0;
        }
        bool first = (lane < s) && (same == 0);
        u64 bal = __ballot(first);
        if (lane < s) sorted[start + rank] = p;
        if (lane == 0) dcount[b] = (u32)__popcll(bal);
    } else if (s <= LDS_CAP) {
        for (int e = lane; e < s; e += 64) li[w][e] = sorted[start + e];
        asm volatile("s_waitcnt lgkmcnt(0) vmcnt(0)" ::: "memory");
        for (int e = lane; e < s; e += 64) {
            u64 p = li[w][e];
            int rank = 0;
            for (int j = 0; j < s; j++) rank += (li[w][j] < p) ? 1 : 0;
            lo[w][rank] = p;
        }
        asm volatile("s_waitcnt lgkmcnt(0)" ::: "memory");
        u32 cnt = 0;
        for (int e = lane; e < s; e += 64) {
            u64 p = lo[w][e];
            sorted[start + e] = p;
            u32 key = (u32)(p >> IDXBITS);
            u32 pk = (e == 0) ? 0xFFFFFFFFu : (u32)(lo[w][e - 1] >> IDXBITS);
            cnt += (key != pk) ? 1u : 0u;
        }
        for (int d = 32; d > 0; d >>= 1) cnt += __shfl_down(cnt, d);
        if (lane == 0) dcount[b] = cnt;
    } else {
        if (lane == 0) {
            for (int j2 = start + 1; j2 < end; j2++) {
                u64 pj = sorted[j2];
                int k2 = j2 - 1;
                while (k2 >= start && sorted[k2] > pj) { sorted[k2 + 1] = sorted[k2]; k2--; }
                sorted[k2 + 1] = pj;
            }
            u32 cnt = 1;
            for (int j2 = start + 1; j2 < end; j2++)
                cnt += ((u32)(sorted[j2] >> IDXBITS) != (u32)(sorted[j2 - 1] >> IDXBITS)) ? 1u : 0u;
            dcount[b] = cnt;
        }
    }
}

// ======== emit: per-point gid (v2p), per-voxel start, num_voxels ========
__global__ void k_emit(const u32* __restrict__ hist, const u32* __restrict__ gidbase,
                       const u64* __restrict__ sorted, float* __restrict__ v2p,
                       u32* __restrict__ voxstart, u32* __restrict__ nvslot, int N) {
    int w = threadIdx.x >> 6;
    int lane = threadIdx.x & 63;
    u32 b = blockIdx.x * SORT_WAVES + (u32)w;
    if (b >= NBUCK) return;
    int end = (int)hist[b];
    int start = b ? (int)hist[b - 1] : 0;
    int s = end - start;
    if (s == 0) return;
    u32 base = gidbase[b];
    u32 carry = 0;
    u32 prevlast = 0xFFFFFFFFu;
    for (int off = 0; off < s; off += 64) {
        int e = off + lane;
        bool valid = e < s;
        u64 p = valid ? sorted[start + e] : 0;
        u32 key = (u32)(p >> IDXBITS);
        u32 idx = (u32)p & IMASK;
        u32 pk = __shfl_up(key, 1);
        if (lane == 0) pk = (off == 0) ? 0xFFFFFFFFu : prevlast;
        u32 f = (valid && key != pk) ? 1u : 0u;
        u32 pf = f;
        for (int d = 1; d < 64; d <<= 1) {
            u32 t = __shfl_up(pf, d);
            if (lane >= d) pf += t;
        }
        u32 gid = base + carry + pf - 1u;
        if (valid) {
            v2p[idx] = (float)gid;
            if (f) voxstart[gid] = (u32)(start + e);
            if (start + e == N - 1) { voxstart[gid + 1] = (u32)N; nvslot[0] = gid + 1u; }
        }
        carry += __shfl(pf, 63);
        prevlast = __shfl(key, 63);
    }
}

// ======== per-voxel outputs + padding zeros (thread per output row) ========
__global__ void k_vox(const u32* __restrict__ voxstart, const u64* __restrict__ sorted,
                      const u32* __restrict__ invrank, const float* __restrict__ feats,
                      const u32* __restrict__ nvslot, float* __restrict__ vox_feats,
                      float* __restrict__ vox_coords, float* __restrict__ nvox, int N) {
    int t = blockIdx.x * blockDim.x + threadIdx.x;
    if (t >= N) return;
    u32 nv = nvslot[0];
    if (t == 0) nvox[0] = (float)nv;
    if ((u32)t >= nv) {
        float4 z = {0, 0, 0, 0};
        float4* vf = (float4*)(vox_feats + (size_t)t * 16);
        vf[0] = z; vf[1] = z; vf[2] = z; vf[3] = z;
        *(float4*)(vox_coords + (size_t)t * 4) = z;
        return;
    }
    u32 s0 = voxstart[t];
    u32 s1 = voxstart[t + 1];
    u64 p0 = sorted[s0];
    u32 kk = (u32)(p0 >> IDXBITS);
    float4 a0 = {0, 0, 0, 0}, a1 = {0, 0, 0, 0}, a2 = {0, 0, 0, 0}, a3 = {0, 0, 0, 0};
    // entries are (key,idx)-sorted: ascending original index => bit-exact segment sum
    for (u32 e = s0; e < s1; e++) {
        u32 idx = (u32)sorted[e] & IMASK;
        const float4* f = (const float4*)(feats + (size_t)idx * 16);
        float4 v0 = f[0], v1 = f[1], v2 = f[2], v3 = f[3];
        a0.x += v0.x; a0.y += v0.y; a0.z += v0.z; a0.w += v0.w;
        a1.x += v1.x; a1.y += v1.y; a1.z += v1.z; a1.w += v1.w;
        a2.x += v2.x; a2.y += v2.y; a2.z += v2.z; a2.w += v2.w;
        a3.x += v3.x; a3.y += v3.y; a3.z += v3.z; a3.w += v3.w;
    }
    float fc = (float)(s1 - s0);
    float4* vf = (float4*)(vox_feats + (size_t)t * 16);
    vf[0] = make_float4(a0.x / fc, a0.y / fc, a0.z / fc, a0.w / fc);
    vf[1] = make_float4(a1.x / fc, a1.y / fc, a1.z / fc, a1.w / fc);
    vf[2] = make_float4(a2.x / fc, a2.y / fc, a2.z / fc, a2.w / fc);
    vf[3] = make_float4(a3.x / fc, a3.y / fc, a3.z / fc, a3.w / fc);
    u32 iv = invrank[kk >> 6];
    u32 tau = iv >> 6;
    u32 c3 = (kk ^ iv) & 63u;
    *(float4*)(vox_coords + (size_t)t * 4) =
        make_float4((float)(tau / 2304u), (float)((tau % 2304u) / 48u),
                    (float)(tau % 48u), (float)c3);
}

extern "C" void kernel_launch(void* const* d_in, const int* in_sizes, int n_in,
                              void* d_out, int out_size, void* d_ws, size_t ws_size,
                              hipStream_t stream) {
    const int* coords = (const int*)d_in[0];
    const float* feats = (const float*)d_in[1];
    int N = in_sizes[0] / 4;

    float* out = (float*)d_out;
    float* vox_feats = out;                      // N*16
    float* vox_coords = out + (size_t)N * 16;    // N*4
    float* v2p = vox_coords + (size_t)N * 4;     // N
    float* nvox = v2p + (size_t)N;               // 1

    char* w = (char*)d_ws;
    u64* pkey64 = (u64*)w;     w += (size_t)N * 8;       // 16 MB
    u64* sorted = (u64*)w;     w += (size_t)N * 8;       // 16 MB
    u32* hist = (u32*)w;       w += (size_t)NBUCK * 4;   // 1 MB
    u32* dcount = (u32*)w;     w += (size_t)NBUCK * 4;   // 1 MB (-> gidbase)
    u32* voxstart = (u32*)w;   w += ((size_t)N + 1) * 4; // 8 MB
    u32* rank48_d = (u32*)w;   w += (size_t)NTRIP * 4;
    u32* invrank_d = (u32*)w;  w += (size_t)NTRIP * 4;
    u32* sums = (u32*)w;       w += (size_t)2048 * 4;
    u32* nvslot = (u32*)w;     w += 256;

    hipMemcpyAsync(rank48_d, g_rank48, sizeof(g_rank48), hipMemcpyHostToDevice, stream);
    hipMemsetAsync(hist, 0, (size_t)NBUCK * 4, stream);

    int blocksN = (N + 255) / 256;
    int blocksT = (NTRIP + 255) / 256;
    int blocksB = (int)(NBUCK / SORT_WAVES);     // 65536 wave-per-bucket blocks
    int nch = (int)(NBUCK / SCAN_CHUNK);         // 128

    k_invrank<<<blocksT, 256, 0, stream>>>(rank48_d, invrank_d);
    k_pkeys<<<blocksN, 256, 0, stream>>>(coords, rank48_d, hist, pkey64, N);

    // exclusive scan of bucket histogram
    k_scan_chunks<true><<<nch, SCAN_T, 0, stream>>>(hist, (int)NBUCK, sums);
    k_scan_single<<<1, SCAN_T, 0, stream>>>(sums, nch);
    k_scan_add<<<(int)(NBUCK / 256), 256, 0, stream>>>(hist, (int)NBUCK, sums);

    k_scatter64<<<blocksN, 256, 0, stream>>>(pkey64, hist, sorted, N);
    k_bucket_sort64<<<blocksB, 256, 0, stream>>>(hist, sorted, dcount);

    // exclusive scan of per-bucket distinct counts -> gid bases
    k_scan_chunks<true><<<nch, SCAN_T, 0, stream>>>(dcount, (int)NBUCK, sums);
    k_scan_single<<<1, SCAN_T, 0, stream>>>(sums, nch);
    k_scan_add<<<(int)(NBUCK / 256), 256, 0, stream>>>(dcount, (int)NBUCK, sums);

    k_emit<<<blocksB, 256, 0, stream>>>(hist, dcount, sorted, v2p, voxstart, nvslot, N);
    k_vox<<<blocksN, 256, 0, stream>>>(voxstart, sorted, invrank_d, feats, nvslot,
                                       vox_feats, vox_coords, nvox, N);
}

// Round 9
// 375.743 us; speedup vs baseline: 1.4769x; 1.4769x over previous
//
#include <hip/hip_runtime.h>
#include <vector>
#include <algorithm>
#include <utility>

typedef unsigned long long u64;
typedef unsigned int u32;

#define NTRIP 110592              // 48^3 distinct (c0,c1,c2)
#define IDXBITS 21
#define IMASK ((1u << IDXBITS) - 1)
#define NCOARSE 512               // top 9 bits of 23-bit key
#define CAPB 5632                 // pass-B LDS capacity (avg 4630, 13 sigma headroom)
#define NSUB 4096                 // pass-B sub-bins (next 12 key bits)
#define PK_E 8                    // elems/thread, pkeys
#define PA_E 16                   // elems/thread, pass A (4096/block)
#define SORT_WAVES 4

// ======== host-side: rank table for the 110,592 triple-hashes ========
// full hash = fnv3p(c0,c1,c2) ^ c3 (c3 < 64 flips only low 6 bits).
// rank48[tau] = (rank_of_hash << 6) | (hash & 63); point key = rank48[tau]^c3 (23 bits)
static u32 g_rank48[NTRIP];
namespace {
struct RankInit {
    RankInit() {
        std::vector<std::pair<u64, u32>> v(NTRIP);
        for (u32 t = 0; t < NTRIP; t++) {
            u64 h = 14695981039346656037ull;
            const u64 P = 1099511628211ull;
            h *= P; h ^= (u64)(t / 2304);
            h *= P; h ^= (u64)((t % 2304) / 48);
            h *= P; h ^= (u64)(t % 48);
            h *= P;
            v[t] = {h, t};
        }
        std::sort(v.begin(), v.end());
        for (u32 p = 0; p < NTRIP; p++)
            g_rank48[v[p].second] = (p << 6) | (u32)(v[p].first & 63ull);
    }
};
static RankInit g_rank_init;
}

__global__ void k_invrank(const u32* __restrict__ rank48, u32* __restrict__ invrank) {
    int tau = blockIdx.x * blockDim.x + threadIdx.x;
    if (tau >= NTRIP) return;
    u32 r = rank48[tau];
    invrank[r >> 6] = ((u32)tau << 6) | (r & 63u);
}

// ======== packed keys + coarse histogram (LDS-aggregated) ========
__global__ void k_pkeys(const int* __restrict__ coords, const u32* __restrict__ rank48,
                        u32* __restrict__ hist, u64* __restrict__ pkey64, int N) {
    __shared__ u32 lh[NCOARSE];
    int tid = threadIdx.x;
    for (int d = tid; d < NCOARSE; d += 256) lh[d] = 0;
    __syncthreads();
    int base = blockIdx.x * (256 * PK_E);
#pragma unroll
    for (int k = 0; k < PK_E; k++) {
        int i = base + k * 256 + tid;
        if (i < N) {
            int4 c = ((const int4*)coords)[i];
            u32 tau = (u32)c.x * 2304u + (u32)c.y * 48u + (u32)c.z;
            u32 kk = rank48[tau] ^ (u32)c.w;
            pkey64[i] = ((u64)kk << IDXBITS) | (u32)i;
            atomicAdd(&lh[kk >> 14], 1u);
        }
    }
    __syncthreads();
    for (int d = tid; d < NCOARSE; d += 256)
        if (lh[d]) atomicAdd(&hist[d], lh[d]);
}

// ======== exclusive scan of 512 values, one block; optional cursor copy ========
__global__ void k_scan512(const u32* __restrict__ in, u32* __restrict__ out,
                          u32* __restrict__ cursor) {
    __shared__ u32 s[256];
    int t = threadIdx.x;
    u32 a = in[2 * t], b = in[2 * t + 1];
    u32 sum = a + b;
    s[t] = sum;
    __syncthreads();
    for (int off = 1; off < 256; off <<= 1) {
        u32 v = (t >= off) ? s[t - off] : 0u;
        __syncthreads();
        s[t] += v;
        __syncthreads();
    }
    u32 tb = s[t] - sum;
    out[2 * t] = tb;
    out[2 * t + 1] = tb + a;
    if (cursor) { cursor[2 * t] = tb; cursor[2 * t + 1] = tb + a; }
    if (t == 255) out[512] = s[255];
}

// ======== pass A: coarse scatter with block-level LDS binning ========
__global__ void k_passA(const u64* __restrict__ pkey64, u32* __restrict__ cursor,
                        u64* __restrict__ sorted, int N) {
    __shared__ u32 lh[NCOARSE], lclaim[NCOARSE], lcnt[NCOARSE];
    int tid = threadIdx.x;
    for (int d = tid; d < NCOARSE; d += 256) { lh[d] = 0; lcnt[d] = 0; }
    __syncthreads();
    int base = blockIdx.x * (256 * PA_E);
    u64 p[PA_E];
    bool val[PA_E];
#pragma unroll
    for (int k = 0; k < PA_E; k++) {
        int i = base + k * 256 + tid;
        val[k] = i < N;
        p[k] = val[k] ? pkey64[i] : 0;
        if (val[k]) atomicAdd(&lh[(u32)(p[k] >> 35)], 1u);
    }
    __syncthreads();
    for (int d = tid; d < NCOARSE; d += 256) {
        u32 c = lh[d];
        lclaim[d] = c ? atomicAdd(&cursor[d], c) : 0u;
    }
    __syncthreads();
#pragma unroll
    for (int k = 0; k < PA_E; k++) {
        if (val[k]) {
            u32 d = (u32)(p[k] >> 35);
            u32 r = atomicAdd(&lcnt[d], 1u);
            sorted[lclaim[d] + r] = p[k];
        }
    }
}

// ======== pass B: in-LDS counting-sort refinement per coarse bucket ========
__global__ __launch_bounds__(256) void k_passB(const u32* __restrict__ base,
                                               u64* __restrict__ sorted,
                                               u32* __restrict__ dcount) {
    __shared__ u64 lout[CAPB];
    __shared__ u32 lbase[NSUB];
    __shared__ u32 lcnt[NSUB];
    __shared__ u32 lpart[256];
    int tid = threadIdx.x;
    int b = blockIdx.x;
    u32 s0 = base[b], s1 = base[b + 1];
    int s = (int)(s1 - s0);
    if (s == 0) { if (tid == 0) dcount[b] = 0; return; }
    if (s > CAPB) {  // statistically never; correctness insurance
        if (tid == 0) {
            for (int j = (int)s0 + 1; j < (int)s1; j++) {
                u64 pj = sorted[j];
                int k2 = j - 1;
                while (k2 >= (int)s0 && sorted[k2] > pj) { sorted[k2 + 1] = sorted[k2]; k2--; }
                sorted[k2 + 1] = pj;
            }
            u32 c = 1;
            for (int j = (int)s0 + 1; j < (int)s1; j++)
                c += ((u32)(sorted[j] >> IDXBITS) != (u32)(sorted[j - 1] >> IDXBITS)) ? 1u : 0u;
            dcount[b] = c;
        }
        return;
    }
    for (int d = tid; d < NSUB; d += 256) { lbase[d] = 0; lcnt[d] = 0; }
    __syncthreads();
    u64 p[22];  // CAPB/256 = 22
#pragma unroll
    for (int k = 0; k < 22; k++) {
        int e = k * 256 + tid;
        if (e < s) {
            p[k] = sorted[s0 + e];
            atomicAdd(&lbase[(u32)(p[k] >> 23) & 0xFFFu], 1u);
        }
    }
    __syncthreads();
    // exclusive scan of NSUB bins; thread t owns bins [16t, 16t+16)
    u32 mycnt[16];
    u32 run = 0;
#pragma unroll
    for (int k = 0; k < 16; k++) { mycnt[k] = lbase[tid * 16 + k]; run += mycnt[k]; }
    lpart[tid] = run;
    __syncthreads();
    for (int off = 1; off < 256; off <<= 1) {
        u32 v = (tid >= off) ? lpart[tid - off] : 0u;
        __syncthreads();
        lpart[tid] += v;
        __syncthreads();
    }
    u32 tb = lpart[tid] - run;
#pragma unroll
    for (int k = 0; k < 16; k++) { u32 c = mycnt[k]; lbase[tid * 16 + k] = tb; tb += c; }
    __syncthreads();
    // placement into sub-bins
#pragma unroll
    for (int k = 0; k < 22; k++) {
        int e = k * 256 + tid;
        if (e < s) {
            u32 d = (u32)(p[k] >> 23) & 0xFFFu;
            u32 slot = lbase[d] + atomicAdd(&lcnt[d], 1u);
            lout[slot] = p[k];
        }
    }
    __syncthreads();
    // cleanup: full-u64 insertion sort inside each sub-bin (avg ~1 elem)
    for (int d = tid; d < NSUB; d += 256) {
        u32 c = lcnt[d];
        if (c >= 2) {
            u32 st = lbase[d];
            for (u32 j = st + 1; j < st + c; j++) {
                u64 pj = lout[j];
                int k2 = (int)j - 1;
                while (k2 >= (int)st && lout[k2] > pj) { lout[k2 + 1] = lout[k2]; k2--; }
                lout[k2 + 1] = pj;
            }
        }
    }
    __syncthreads();
    // coalesced write-back + distinct-key count
    u32 cnt = 0;
    for (int e = tid; e < s; e += 256) {
        u64 pv = lout[e];
        sorted[s0 + e] = pv;
        u32 key = (u32)(pv >> IDXBITS);
        u32 pk = (e == 0) ? 0xFFFFFFFFu : (u32)(lout[e - 1] >> IDXBITS);
        cnt += (key != pk) ? 1u : 0u;
    }
    lpart[tid] = cnt;
    __syncthreads();
    for (int off = 128; off > 0; off >>= 1) {
        if (tid < off) lpart[tid] += lpart[tid + off];
        __syncthreads();
    }
    if (tid == 0) dcount[b] = lpart[0];
}

// ======== emit: per-point gid (v2p), per-voxel start, num_voxels ========
__global__ void k_emit(const u32* __restrict__ base, const u32* __restrict__ gidbase,
                       const u64* __restrict__ sorted, float* __restrict__ v2p,
                       u32* __restrict__ voxstart, u32* __restrict__ nvslot, int N) {
    int w = threadIdx.x >> 6;
    int lane = threadIdx.x & 63;
    u32 b = blockIdx.x * SORT_WAVES + (u32)w;
    if (b >= NCOARSE) return;
    int start = (int)base[b], end = (int)base[b + 1];
    int s = end - start;
    if (s == 0) return;
    u32 gb = gidbase[b];
    u32 carry = 0;
    u32 prevlast = 0xFFFFFFFFu;
    for (int off = 0; off < s; off += 64) {
        int e = off + lane;
        bool valid = e < s;
        u64 p = valid ? sorted[start + e] : 0;
        u32 key = (u32)(p >> IDXBITS);
        u32 idx = (u32)p & IMASK;
        u32 pk = __shfl_up(key, 1);
        if (lane == 0) pk = (off == 0) ? 0xFFFFFFFFu : prevlast;
        u32 f = (valid && key != pk) ? 1u : 0u;
        u32 pf = f;
        for (int d = 1; d < 64; d <<= 1) {
            u32 t = __shfl_up(pf, d);
            if (lane >= d) pf += t;
        }
        u32 gid = gb + carry + pf - 1u;
        if (valid) {
            v2p[idx] = (float)gid;
            if (f) voxstart[gid] = (u32)(start + e);
            if (start + e == N - 1) { voxstart[gid + 1] = (u32)N; nvslot[0] = gid + 1u; }
        }
        carry += __shfl(pf, 63);
        prevlast = __shfl(key, 63);
    }
}

// ======== per-voxel outputs + padding zeros ========
__global__ void k_vox(const u32* __restrict__ voxstart, const u64* __restrict__ sorted,
                      const u32* __restrict__ invrank, const float* __restrict__ feats,
                      const u32* __restrict__ nvslot, float* __restrict__ vox_feats,
                      float* __restrict__ vox_coords, float* __restrict__ nvox, int N) {
    int t = blockIdx.x * blockDim.x + threadIdx.x;
    if (t >= N) return;
    u32 nv = nvslot[0];
    if (t == 0) nvox[0] = (float)nv;
    if ((u32)t >= nv) {
        float4 z = {0, 0, 0, 0};
        float4* vf = (float4*)(vox_feats + (size_t)t * 16);
        vf[0] = z; vf[1] = z; vf[2] = z; vf[3] = z;
        *(float4*)(vox_coords + (size_t)t * 4) = z;
        return;
    }
    u32 s0 = voxstart[t];
    u32 s1 = voxstart[t + 1];
    u64 p0 = sorted[s0];
    u32 kk = (u32)(p0 >> IDXBITS);
    float4 a0 = {0, 0, 0, 0}, a1 = {0, 0, 0, 0}, a2 = {0, 0, 0, 0}, a3 = {0, 0, 0, 0};
    for (u32 e = s0; e < s1; e++) {
        u32 idx = (u32)sorted[e] & IMASK;
        const float4* f = (const float4*)(feats + (size_t)idx * 16);
        float4 v0 = f[0], v1 = f[1], v2 = f[2], v3 = f[3];
        a0.x += v0.x; a0.y += v0.y; a0.z += v0.z; a0.w += v0.w;
        a1.x += v1.x; a1.y += v1.y; a1.z += v1.z; a1.w += v1.w;
        a2.x += v2.x; a2.y += v2.y; a2.z += v2.z; a2.w += v2.w;
        a3.x += v3.x; a3.y += v3.y; a3.z += v3.z; a3.w += v3.w;
    }
    float fc = (float)(s1 - s0);
    float4* vf = (float4*)(vox_feats + (size_t)t * 16);
    vf[0] = make_float4(a0.x / fc, a0.y / fc, a0.z / fc, a0.w / fc);
    vf[1] = make_float4(a1.x / fc, a1.y / fc, a1.z / fc, a1.w / fc);
    vf[2] = make_float4(a2.x / fc, a2.y / fc, a2.z / fc, a2.w / fc);
    vf[3] = make_float4(a3.x / fc, a3.y / fc, a3.z / fc, a3.w / fc);
    u32 iv = invrank[kk >> 6];
    u32 tau = iv >> 6;
    u32 c3 = (kk ^ iv) & 63u;
    *(float4*)(vox_coords + (size_t)t * 4) =
        make_float4((float)(tau / 2304u), (float)((tau % 2304u) / 48u),
                    (float)(tau % 48u), (float)c3);
}

extern "C" void kernel_launch(void* const* d_in, const int* in_sizes, int n_in,
                              void* d_out, int out_size, void* d_ws, size_t ws_size,
                              hipStream_t stream) {
    const int* coords = (const int*)d_in[0];
    const float* feats = (const float*)d_in[1];
    int N = in_sizes[0] / 4;

    float* out = (float*)d_out;
    float* vox_feats = out;                      // N*16
    float* vox_coords = out + (size_t)N * 16;    // N*4
    float* v2p = vox_coords + (size_t)N * 4;     // N
    float* nvox = v2p + (size_t)N;               // 1

    char* w = (char*)d_ws;
    u64* pkey64 = (u64*)w;     w += (size_t)N * 8;        // 16 MB
    u64* sorted = (u64*)w;     w += (size_t)N * 8;        // 16 MB
    u32* hist = (u32*)w;       w += 512 * 4;
    u32* basearr = (u32*)w;    w += 513 * 4;
    u32* cursor = (u32*)w;     w += 512 * 4;
    u32* dcount = (u32*)w;     w += 512 * 4;
    u32* gidbase = (u32*)w;    w += 513 * 4;
    u32* voxstart = (u32*)w;   w += ((size_t)N + 1) * 4;  // 8 MB
    u32* rank48_d = (u32*)w;   w += (size_t)NTRIP * 4;
    u32* invrank_d = (u32*)w;  w += (size_t)NTRIP * 4;
    u32* nvslot = (u32*)w;     w += 256;

    hipMemcpyAsync(rank48_d, g_rank48, sizeof(g_rank48), hipMemcpyHostToDevice, stream);
    hipMemsetAsync(hist, 0, 512 * 4, stream);

    int blocksT = (NTRIP + 255) / 256;
    int blocksPK = (N + 256 * PK_E - 1) / (256 * PK_E);
    int blocksPA = (N + 256 * PA_E - 1) / (256 * PA_E);
    int blocksN = (N + 255) / 256;

    k_invrank<<<blocksT, 256, 0, stream>>>(rank48_d, invrank_d);
    k_pkeys<<<blocksPK, 256, 0, stream>>>(coords, rank48_d, hist, pkey64, N);
    k_scan512<<<1, 256, 0, stream>>>(hist, basearr, cursor);
    k_passA<<<blocksPA, 256, 0, stream>>>(pkey64, cursor, sorted, N);
    k_passB<<<NCOARSE, 256, 0, stream>>>(basearr, sorted, dcount);
    k_scan512<<<1, 256, 0, stream>>>(dcount, gidbase, (u32*)nullptr);
    k_emit<<<NCOARSE / SORT_WAVES, 256, 0, stream>>>(basearr, gidbase, sorted, v2p,
                                                     voxstart, nvslot, N);
    k_vox<<<blocksN, 256, 0, stream>>>(voxstart, sorted, invrank_d, feats, nvslot,
                                       vox_feats, vox_coords, nvox, N);
}